// Round 3
// baseline (317.395 us; speedup 1.0000x reference)
//
#include <hip/hip_runtime.h>
#include <cstdint>

#define N_NODES 50000
#define IN_DIM 256
#define OUT_DIM 512
#define NUM_HASH 8
#define HASH_DIM 256
#define N_EDGES 800000
#define SCAN_BLOCKS ((N_NODES + 255) / 256)  // 196

typedef unsigned short ushort_t;
typedef __attribute__((ext_vector_type(8))) short short8;
typedef __attribute__((ext_vector_type(4))) float f32x4;

__device__ __forceinline__ ushort_t f2bf(float f) {
  uint32_t u = __builtin_bit_cast(uint32_t, f);
  u = (u + 0x7fffu + ((u >> 16) & 1u)) >> 16;
  return (ushort_t)u;
}
__device__ __forceinline__ float bf2f(uint32_t u) {
  return __builtin_bit_cast(float, u << 16);
}

__device__ __forceinline__ void gload_lds16(const void* g, void* l) {
  __builtin_amdgcn_global_load_lds((const __attribute__((address_space(1))) void*)g,
                                   (__attribute__((address_space(3))) void*)l, 16, 0, 0);
}

// ---- convert x (f32) -> x_bf (bf16), 4 elems/thread ----
__global__ void cvt_x_kernel(const float* __restrict__ x, ushort_t* __restrict__ xbf) {
  int g = blockIdx.x * 256 + threadIdx.x;
  float4 v = reinterpret_cast<const float4*>(x)[g];
  uint2 pack;
  pack.x = (uint32_t)f2bf(v.x) | ((uint32_t)f2bf(v.y) << 16);
  pack.y = (uint32_t)f2bf(v.z) | ((uint32_t)f2bf(v.w) << 16);
  *reinterpret_cast<uint2*>(xbf + (size_t)g * 4) = pack;
}

// ---- degree count ----
__global__ void deg_kernel(const int* __restrict__ dst, int* __restrict__ deg) {
  int e = blockIdx.x * 256 + threadIdx.x;
  atomicAdd(&deg[dst[e]], 1);
}

// ---- scan phase 1: per-block (256-elem) sums ----
__global__ void scan_bsum_kernel(const int* __restrict__ deg, int* __restrict__ bsum) {
  __shared__ int ws[4];
  const int t = threadIdx.x;
  const int i = blockIdx.x * 256 + t;
  int v = (i < N_NODES) ? deg[i] : 0;
#pragma unroll
  for (int d = 1; d < 64; d <<= 1) v += __shfl_xor(v, d, 64);
  if ((t & 63) == 0) ws[t >> 6] = v;
  __syncthreads();
  if (t == 0) bsum[blockIdx.x] = ws[0] + ws[1] + ws[2] + ws[3];
}

// ---- scan phase 2: single block exclusive-scans the 196 block sums ----
__global__ void scan_bscan_kernel(const int* __restrict__ bsum, int* __restrict__ boff) {
  __shared__ int tmp[256];
  const int t = threadIdx.x;
  int v = (t < SCAN_BLOCKS) ? bsum[t] : 0;
  tmp[t] = v;
  __syncthreads();
#pragma unroll
  for (int d = 1; d < 256; d <<= 1) {
    int add = (t >= d) ? tmp[t - d] : 0;
    __syncthreads();
    tmp[t] += add;
    __syncthreads();
  }
  boff[t] = (t == 0) ? 0 : tmp[t - 1];
}

// ---- scan phase 3: per-block inclusive scan + base, write offsets & cursor ----
__global__ void scan_final_kernel(const int* __restrict__ deg, const int* __restrict__ boff,
                                  int* __restrict__ offsets, int* __restrict__ cursor) {
  __shared__ int tmp[256];
  const int t = threadIdx.x;
  const int i = blockIdx.x * 256 + t;
  int v = (i < N_NODES) ? deg[i] : 0;
  tmp[t] = v;
  __syncthreads();
#pragma unroll
  for (int d = 1; d < 256; d <<= 1) {
    int add = (t >= d) ? tmp[t - d] : 0;
    __syncthreads();
    tmp[t] += add;
    __syncthreads();
  }
  const int excl = tmp[t] - v + boff[blockIdx.x];
  if (i < N_NODES) {
    offsets[i] = excl;
    cursor[i] = excl;
  }
  if (i == 0) offsets[N_NODES] = N_EDGES;
}

// ---- CSR fill ----
__global__ void fill_kernel(const int* __restrict__ src, const int* __restrict__ dst,
                            int* __restrict__ cursor, int* __restrict__ csr) {
  int e = blockIdx.x * 256 + threadIdx.x;
  int d = dst[e];
  int pos = atomicAdd(&cursor[d], 1);
  csr[pos] = src[e];
}

// ---- segment mean: one wave per node, 4 bf16/lane ----
__global__ void agg_kernel(const ushort_t* __restrict__ xbf, const int* __restrict__ offsets,
                           const int* __restrict__ csr, ushort_t* __restrict__ basebf) {
  int wid = (blockIdx.x * 256 + threadIdx.x) >> 6;
  int lane = threadIdx.x & 63;
  if (wid >= N_NODES) return;
  int off = offsets[wid], end = offsets[wid + 1];
  float a0 = 0.f, a1 = 0.f, a2 = 0.f, a3 = 0.f;
  for (int i = off; i < end; ++i) {
    int s = csr[i];
    uint2 v = *reinterpret_cast<const uint2*>(xbf + (size_t)s * IN_DIM + lane * 4);
    a0 += bf2f(v.x & 0xffffu);
    a1 += bf2f(v.x >> 16);
    a2 += bf2f(v.y & 0xffffu);
    a3 += bf2f(v.y >> 16);
  }
  int d = end - off;
  if (d > 0) {
    float inv = 1.0f / (float)d;
    a0 *= inv; a1 *= inv; a2 *= inv; a3 *= inv;
  } else {
    uint2 v = *reinterpret_cast<const uint2*>(xbf + (size_t)wid * IN_DIM + lane * 4);
    a0 = bf2f(v.x & 0xffffu);
    a1 = bf2f(v.x >> 16);
    a2 = bf2f(v.y & 0xffffu);
    a3 = bf2f(v.y >> 16);
  }
  uint2 o;
  o.x = (uint32_t)f2bf(a0) | ((uint32_t)f2bf(a1) << 16);
  o.y = (uint32_t)f2bf(a2) | ((uint32_t)f2bf(a3) << 16);
  *reinterpret_cast<uint2*>(basebf + (size_t)wid * IN_DIM + lane * 4) = o;
}

// ---- extract (col, sign) from signed one-hot hash mats ----
__global__ void extract_kernel(const float* __restrict__ hm, int* __restrict__ col,
                               float* __restrict__ sign) {
  const int t = blockIdx.x * 256 + threadIdx.x;  // 2048 = (h,i)
  const float* row = hm + (size_t)t * HASH_DIM;
  int c = 0;
  float s = 0.f;
  for (int j = 0; j < HASH_DIM; ++j) {
    float v = row[j];
    if (v != 0.f) { c = j; s = v; }
  }
  col[t] = c;
  sign[t] = s;
}

// ---- build combined B^T [OUT=512 rows][K=512 cols] bf16 ----
__global__ void build_wct_kernel(const float* __restrict__ Wpost, const float* __restrict__ Wself,
                                 const int* __restrict__ col, const float* __restrict__ sign,
                                 ushort_t* __restrict__ wct) {
  const int k = blockIdx.x;  // 0..511
#pragma unroll
  for (int t = 0; t < 2; ++t) {
    const int o = threadIdx.x + t * 256;
    float acc;
    if (k < 256) {
      acc = 0.f;
      for (int h = 0; h < NUM_HASH; ++h) {
        const int c = col[h * 256 + k];
        const float s = sign[h * 256 + k];
        acc += s * Wpost[(size_t)(h * 256 + c) * OUT_DIM + o];
      }
    } else {
      acc = Wself[(size_t)(k - 256) * OUT_DIM + o];
    }
    wct[(size_t)o * 512 + k] = f2bf(acc);
  }
}

// ---- fused GEMM: out = elu([base|x] @ [Weff;Wself] + bias) ----
// 128x128 tile, BK=32, 2-phase pipelined LDS double-buffer.
// LDS layout per buffer: [4 kslots][128 rows][8 elems] -> staging lane c
// maps (slot=c>>7,row=c&127); fragment reads are 16 consecutive lanes over
// 256 contiguous bytes -> bank-conflict-free. Grid: x=bm (391), y=bn (4) so
// the 4 blocks sharing an A-panel don't scatter across XCDs before reuse.
__global__ __launch_bounds__(256) void gemm_kernel(const ushort_t* __restrict__ Abase,
                                                   const ushort_t* __restrict__ Ax,
                                                   const ushort_t* __restrict__ Bt,
                                                   const float* __restrict__ bias,
                                                   float* __restrict__ out) {
  __shared__ __align__(16) ushort_t As[2][4096];  // 2 x 8KB
  __shared__ __align__(16) ushort_t Bs[2][4096];  // 2 x 8KB
  const int tid = threadIdx.x;
  const int lane = tid & 63;
  const int w = tid >> 6;
  const int bm = blockIdx.x, bn = blockIdx.y;
  const int wm = w & 1, wn = w >> 1;
  f32x4 acc[4][4] = {};

  auto stage = [&](int kt, int buf) {
    const ushort_t* Aptr = (kt < 8) ? Abase : Ax;
    const int k0 = (kt & 7) * 32;
#pragma unroll
    for (int j = 0; j < 2; ++j) {
      const int c = j * 256 + tid;  // 0..511
      const int slot = c >> 7, row = c & 127;
      int rg = bm * 128 + row;
      rg = rg < N_NODES ? rg : N_NODES - 1;
      gload_lds16(Aptr + (size_t)rg * IN_DIM + k0 + slot * 8, &As[buf][c * 8]);
      const int rb = bn * 128 + row;
      gload_lds16(Bt + (size_t)rb * 512 + kt * 32 + slot * 8, &Bs[buf][c * 8]);
    }
  };

  stage(0, 0);
  __syncthreads();

  const int fr = lane & 15, sl = lane >> 4;
  int cur = 0;
  for (int kt = 0; kt < 16; ++kt) {
    if (kt < 15) stage(kt + 1, cur ^ 1);
    short8 af[4], bfr[4];
#pragma unroll
    for (int i = 0; i < 4; ++i)
      af[i] = *reinterpret_cast<const short8*>(
          &As[cur][(sl * 128 + wm * 64 + i * 16 + fr) * 8]);
#pragma unroll
    for (int j = 0; j < 4; ++j)
      bfr[j] = *reinterpret_cast<const short8*>(
          &Bs[cur][(sl * 128 + wn * 64 + j * 16 + fr) * 8]);
#pragma unroll
    for (int i = 0; i < 4; ++i)
#pragma unroll
      for (int j = 0; j < 4; ++j)
        acc[i][j] = __builtin_amdgcn_mfma_f32_16x16x32_bf16(af[i], bfr[j], acc[i][j], 0, 0, 0);
    __syncthreads();
    cur ^= 1;
  }

  const int row0 = bm * 128 + wm * 64;
  const int col0 = bn * 128 + wn * 64;
#pragma unroll
  for (int j = 0; j < 4; ++j) {
    const int colg = col0 + j * 16 + (lane & 15);
    const float b = bias[colg];
#pragma unroll
    for (int i = 0; i < 4; ++i) {
#pragma unroll
      for (int r = 0; r < 4; ++r) {
        const int rowg = row0 + i * 16 + (lane >> 4) * 4 + r;
        if (rowg < N_NODES) {
          float v = acc[i][j][r] + b;
          out[(size_t)rowg * OUT_DIM + colg] = v > 0.f ? v : expm1f(v);
        }
      }
    }
  }
}

extern "C" void kernel_launch(void* const* d_in, const int* in_sizes, int n_in,
                              void* d_out, int out_size, void* d_ws, size_t ws_size,
                              hipStream_t stream) {
  const float* x = (const float*)d_in[0];
  const float* Wpost = (const float*)d_in[1];
  const float* Wself = (const float*)d_in[2];
  const float* bias = (const float*)d_in[3];
  const float* hm = (const float*)d_in[4];
  const int* esrc = (const int*)d_in[5];
  const int* edst = (const int*)d_in[6];
  float* out = (float*)d_out;

  char* ws = (char*)d_ws;
  ushort_t* xbf = (ushort_t*)ws;   ws += 25600000;   // 50000*256*2
  ushort_t* basebf = (ushort_t*)ws; ws += 25600000;  // 50000*256*2
  ushort_t* wct = (ushort_t*)ws;   ws += 524288;     // 512*512*2
  int* colb = (int*)ws;            ws += 8192;       // 2048*4
  float* signb = (float*)ws;       ws += 8192;       // 2048*4
  int* deg = (int*)ws;             ws += 200192;     // 50000*4 (padded)
  int* offsets = (int*)ws;         ws += 200704;     // 50001*4 (padded)
  int* cursor = (int*)ws;          ws += 200192;     // 50000*4 (padded)
  int* bsum = (int*)ws;            ws += 1024;       // 196*4 (padded)
  int* boff = (int*)ws;            ws += 1024;       // 256*4
  int* csr = (int*)ws;             ws += 3200000;    // 800000*4

  hipMemsetAsync(deg, 0, (size_t)N_NODES * 4, stream);
  cvt_x_kernel<<<12500, 256, 0, stream>>>(x, xbf);
  deg_kernel<<<3125, 256, 0, stream>>>(edst, deg);
  scan_bsum_kernel<<<SCAN_BLOCKS, 256, 0, stream>>>(deg, bsum);
  scan_bscan_kernel<<<1, 256, 0, stream>>>(bsum, boff);
  scan_final_kernel<<<SCAN_BLOCKS, 256, 0, stream>>>(deg, boff, offsets, cursor);
  fill_kernel<<<3125, 256, 0, stream>>>(esrc, edst, cursor, csr);
  agg_kernel<<<12500, 256, 0, stream>>>(xbf, offsets, csr, basebf);
  extract_kernel<<<8, 256, 0, stream>>>(hm, colb, signb);
  build_wct_kernel<<<512, 256, 0, stream>>>(Wpost, Wself, colb, signb, wct);
  dim3 ggrid((N_NODES + 127) / 128, 4);
  gemm_kernel<<<ggrid, 256, 0, stream>>>(basebf, xbf, wct, bias, out);
}

// Round 4
// 279.854 us; speedup vs baseline: 1.1341x; 1.1341x over previous
//
#include <hip/hip_runtime.h>
#include <cstdint>

#define N_NODES 50000
#define IN_DIM 256
#define OUT_DIM 512
#define NUM_HASH 8
#define HASH_DIM 256
#define N_EDGES 800000
#define SCAN_BLOCKS ((N_NODES + 255) / 256)  // 196

typedef unsigned short ushort_t;
typedef __attribute__((ext_vector_type(8))) short short8;
typedef __attribute__((ext_vector_type(4))) float f32x4;

__device__ __forceinline__ ushort_t f2bf(float f) {
  uint32_t u = __builtin_bit_cast(uint32_t, f);
  u = (u + 0x7fffu + ((u >> 16) & 1u)) >> 16;
  return (ushort_t)u;
}
__device__ __forceinline__ float bf2f(uint32_t u) {
  return __builtin_bit_cast(float, u << 16);
}

__device__ __forceinline__ void gload_lds16(const void* g, void* l) {
  __builtin_amdgcn_global_load_lds((const __attribute__((address_space(1))) void*)g,
                                   (__attribute__((address_space(3))) void*)l, 16, 0, 0);
}

// ---- convert x (f32) -> x_bf (bf16), 4 elems/thread ----
__global__ void cvt_x_kernel(const float* __restrict__ x, ushort_t* __restrict__ xbf) {
  int g = blockIdx.x * 256 + threadIdx.x;
  float4 v = reinterpret_cast<const float4*>(x)[g];
  uint2 pack;
  pack.x = (uint32_t)f2bf(v.x) | ((uint32_t)f2bf(v.y) << 16);
  pack.y = (uint32_t)f2bf(v.z) | ((uint32_t)f2bf(v.w) << 16);
  *reinterpret_cast<uint2*>(xbf + (size_t)g * 4) = pack;
}

// ---- degree count ----
__global__ void deg_kernel(const int* __restrict__ dst, int* __restrict__ deg) {
  int e = blockIdx.x * 256 + threadIdx.x;
  atomicAdd(&deg[dst[e]], 1);
}

// ---- scan phase 1: per-block (256-elem) sums ----
__global__ void scan_bsum_kernel(const int* __restrict__ deg, int* __restrict__ bsum) {
  __shared__ int ws[4];
  const int t = threadIdx.x;
  const int i = blockIdx.x * 256 + t;
  int v = (i < N_NODES) ? deg[i] : 0;
#pragma unroll
  for (int d = 1; d < 64; d <<= 1) v += __shfl_xor(v, d, 64);
  if ((t & 63) == 0) ws[t >> 6] = v;
  __syncthreads();
  if (t == 0) bsum[blockIdx.x] = ws[0] + ws[1] + ws[2] + ws[3];
}

// ---- scan phase 2: single block exclusive-scans the 196 block sums ----
__global__ void scan_bscan_kernel(const int* __restrict__ bsum, int* __restrict__ boff) {
  __shared__ int tmp[256];
  const int t = threadIdx.x;
  int v = (t < SCAN_BLOCKS) ? bsum[t] : 0;
  tmp[t] = v;
  __syncthreads();
#pragma unroll
  for (int d = 1; d < 256; d <<= 1) {
    int add = (t >= d) ? tmp[t - d] : 0;
    __syncthreads();
    tmp[t] += add;
    __syncthreads();
  }
  boff[t] = (t == 0) ? 0 : tmp[t - 1];
}

// ---- scan phase 3: per-block inclusive scan + base ----
__global__ void scan_final_kernel(const int* __restrict__ deg, const int* __restrict__ boff,
                                  int* __restrict__ offsets, int* __restrict__ cursor) {
  __shared__ int tmp[256];
  const int t = threadIdx.x;
  const int i = blockIdx.x * 256 + t;
  int v = (i < N_NODES) ? deg[i] : 0;
  tmp[t] = v;
  __syncthreads();
#pragma unroll
  for (int d = 1; d < 256; d <<= 1) {
    int add = (t >= d) ? tmp[t - d] : 0;
    __syncthreads();
    tmp[t] += add;
    __syncthreads();
  }
  const int excl = tmp[t] - v + boff[blockIdx.x];
  if (i < N_NODES) {
    offsets[i] = excl;
    cursor[i] = excl;
  }
  if (i == 0) offsets[N_NODES] = N_EDGES;
}

// ---- CSR fill ----
__global__ void fill_kernel(const int* __restrict__ src, const int* __restrict__ dst,
                            int* __restrict__ cursor, int* __restrict__ csr) {
  int e = blockIdx.x * 256 + threadIdx.x;
  int d = dst[e];
  int pos = atomicAdd(&cursor[d], 1);
  csr[pos] = src[e];
}

// ---- segment mean: one wave per node, 2-edge unrolled for MLP ----
__global__ void agg_kernel(const ushort_t* __restrict__ xbf, const int* __restrict__ offsets,
                           const int* __restrict__ csr, ushort_t* __restrict__ basebf) {
  int wid = (blockIdx.x * 256 + threadIdx.x) >> 6;
  int lane = threadIdx.x & 63;
  if (wid >= N_NODES) return;
  int off = offsets[wid], end = offsets[wid + 1];
  float a0 = 0.f, a1 = 0.f, a2 = 0.f, a3 = 0.f;
  float c0 = 0.f, c1 = 0.f, c2 = 0.f, c3 = 0.f;
  int i = off;
  for (; i + 2 <= end; i += 2) {
    int s0 = csr[i], s1 = csr[i + 1];
    uint2 v0 = *reinterpret_cast<const uint2*>(xbf + (size_t)s0 * IN_DIM + lane * 4);
    uint2 v1 = *reinterpret_cast<const uint2*>(xbf + (size_t)s1 * IN_DIM + lane * 4);
    a0 += bf2f(v0.x & 0xffffu);
    a1 += bf2f(v0.x >> 16);
    a2 += bf2f(v0.y & 0xffffu);
    a3 += bf2f(v0.y >> 16);
    c0 += bf2f(v1.x & 0xffffu);
    c1 += bf2f(v1.x >> 16);
    c2 += bf2f(v1.y & 0xffffu);
    c3 += bf2f(v1.y >> 16);
  }
  if (i < end) {
    int s0 = csr[i];
    uint2 v0 = *reinterpret_cast<const uint2*>(xbf + (size_t)s0 * IN_DIM + lane * 4);
    a0 += bf2f(v0.x & 0xffffu);
    a1 += bf2f(v0.x >> 16);
    a2 += bf2f(v0.y & 0xffffu);
    a3 += bf2f(v0.y >> 16);
  }
  a0 += c0; a1 += c1; a2 += c2; a3 += c3;
  int d = end - off;
  if (d > 0) {
    float inv = 1.0f / (float)d;
    a0 *= inv; a1 *= inv; a2 *= inv; a3 *= inv;
  } else {
    uint2 v = *reinterpret_cast<const uint2*>(xbf + (size_t)wid * IN_DIM + lane * 4);
    a0 = bf2f(v.x & 0xffffu);
    a1 = bf2f(v.x >> 16);
    a2 = bf2f(v.y & 0xffffu);
    a3 = bf2f(v.y >> 16);
  }
  uint2 o;
  o.x = (uint32_t)f2bf(a0) | ((uint32_t)f2bf(a1) << 16);
  o.y = (uint32_t)f2bf(a2) | ((uint32_t)f2bf(a3) << 16);
  *reinterpret_cast<uint2*>(basebf + (size_t)wid * IN_DIM + lane * 4) = o;
}

// ---- extract (col, sign) from signed one-hot hash mats ----
__global__ void extract_kernel(const float* __restrict__ hm, int* __restrict__ col,
                               float* __restrict__ sign) {
  const int t = blockIdx.x * 256 + threadIdx.x;  // 2048 = (h,i)
  const float* row = hm + (size_t)t * HASH_DIM;
  int c = 0;
  float s = 0.f;
  for (int j = 0; j < HASH_DIM; ++j) {
    float v = row[j];
    if (v != 0.f) { c = j; s = v; }
  }
  col[t] = c;
  sign[t] = s;
}

// ---- build combined B^T [OUT=512 rows][K=512 cols] bf16 ----
__global__ void build_wct_kernel(const float* __restrict__ Wpost, const float* __restrict__ Wself,
                                 const int* __restrict__ col, const float* __restrict__ sign,
                                 ushort_t* __restrict__ wct) {
  const int k = blockIdx.x;  // 0..511
#pragma unroll
  for (int t = 0; t < 2; ++t) {
    const int o = threadIdx.x + t * 256;
    float acc;
    if (k < 256) {
      acc = 0.f;
      for (int h = 0; h < NUM_HASH; ++h) {
        const int c = col[h * 256 + k];
        const float s = sign[h * 256 + k];
        acc += s * Wpost[(size_t)(h * 256 + c) * OUT_DIM + o];
      }
    } else {
      acc = Wself[(size_t)(k - 256) * OUT_DIM + o];
    }
    wct[(size_t)o * 512 + k] = f2bf(acc);
  }
}

// ---- fused GEMM: out = elu([base|x] @ [Weff;Wself] + bias) ----
// 64x128 tile, BK=32, 2-phase LDS double-buffer, kslot layout (conflict-free),
// flat grid 3128 = 8 XCD chunks x 391; the 4 bn-siblings of each bm land on
// one XCD so the A panel is fetched into that L2 once. Small tile -> 12.2
// blocks/CU queue, ~6 resident -> cross-block overlap hides the per-kt
// vmcnt(0) barrier drain (latency-bound regime, not BW/LDS-bound).
__global__ __launch_bounds__(256, 4) void gemm_kernel(const ushort_t* __restrict__ Abase,
                                                      const ushort_t* __restrict__ Ax,
                                                      const ushort_t* __restrict__ Bt,
                                                      const float* __restrict__ bias,
                                                      float* __restrict__ out) {
  __shared__ __align__(16) ushort_t As[2][2048];  // 2 x 4KB  [4 kslot][64 row][8]
  __shared__ __align__(16) ushort_t Bs[2][4096];  // 2 x 8KB  [4 kslot][128 col][8]
  const int tid = threadIdx.x;
  const int lane = tid & 63;
  const int w = tid >> 6;
  const int fid = blockIdx.x;
  const int l = (fid & 7) * 391 + (fid >> 3);  // XCD-chunk swizzle (3128 = 8*391)
  const int bm = l >> 2, bn = l & 3;
  const int wm = w & 1, wn = w >> 1;
  f32x4 acc[2][4] = {};

  auto stage = [&](int kt, int buf) {
    const ushort_t* Aptr = (kt < 8) ? Abase : Ax;
    const int k0 = (kt & 7) * 32;
    {  // A: 64 rows x 32 k = 4KB, one 16B load/thread
      const int slot = tid >> 6, row = tid & 63;
      int rg = bm * 64 + row;
      rg = rg < N_NODES ? rg : N_NODES - 1;
      gload_lds16(Aptr + (size_t)rg * IN_DIM + k0 + slot * 8, &As[buf][tid * 8]);
    }
#pragma unroll
    for (int j = 0; j < 2; ++j) {  // B: 128 cols x 32 k = 8KB
      const int c = j * 256 + tid;
      const int slot = c >> 7, row = c & 127;
      gload_lds16(Bt + (size_t)(bn * 128 + row) * 512 + kt * 32 + slot * 8, &Bs[buf][c * 8]);
    }
  };

  stage(0, 0);
  __syncthreads();

  const int fr = lane & 15, sl = lane >> 4;
  int cur = 0;
  for (int kt = 0; kt < 16; ++kt) {
    if (kt < 15) stage(kt + 1, cur ^ 1);
    short8 af[2], bfr[4];
#pragma unroll
    for (int i = 0; i < 2; ++i)
      af[i] = *reinterpret_cast<const short8*>(
          &As[cur][(sl * 64 + wm * 32 + i * 16 + fr) * 8]);
#pragma unroll
    for (int j = 0; j < 4; ++j)
      bfr[j] = *reinterpret_cast<const short8*>(
          &Bs[cur][(sl * 128 + wn * 64 + j * 16 + fr) * 8]);
#pragma unroll
    for (int i = 0; i < 2; ++i)
#pragma unroll
      for (int j = 0; j < 4; ++j)
        acc[i][j] = __builtin_amdgcn_mfma_f32_16x16x32_bf16(af[i], bfr[j], acc[i][j], 0, 0, 0);
    __syncthreads();
    cur ^= 1;
  }

  const int row0 = bm * 64 + wm * 32;
  const int col0 = bn * 128 + wn * 64;
#pragma unroll
  for (int j = 0; j < 4; ++j) {
    const int colg = col0 + j * 16 + fr;
    const float b = bias[colg];
#pragma unroll
    for (int i = 0; i < 2; ++i) {
#pragma unroll
      for (int r = 0; r < 4; ++r) {
        const int rowg = row0 + i * 16 + sl * 4 + r;
        if (rowg < N_NODES) {
          float v = acc[i][j][r] + b;
          out[(size_t)rowg * OUT_DIM + colg] = v > 0.f ? v : expm1f(v);
        }
      }
    }
  }
}

extern "C" void kernel_launch(void* const* d_in, const int* in_sizes, int n_in,
                              void* d_out, int out_size, void* d_ws, size_t ws_size,
                              hipStream_t stream) {
  const float* x = (const float*)d_in[0];
  const float* Wpost = (const float*)d_in[1];
  const float* Wself = (const float*)d_in[2];
  const float* bias = (const float*)d_in[3];
  const float* hm = (const float*)d_in[4];
  const int* esrc = (const int*)d_in[5];
  const int* edst = (const int*)d_in[6];
  float* out = (float*)d_out;

  char* ws = (char*)d_ws;
  ushort_t* xbf = (ushort_t*)ws;   ws += 25600000;   // 50000*256*2
  ushort_t* basebf = (ushort_t*)ws; ws += 25600000;  // 50000*256*2
  ushort_t* wct = (ushort_t*)ws;   ws += 524288;     // 512*512*2
  int* colb = (int*)ws;            ws += 8192;       // 2048*4
  float* signb = (float*)ws;       ws += 8192;       // 2048*4
  int* deg = (int*)ws;             ws += 200192;     // 50000*4 (padded)
  int* offsets = (int*)ws;         ws += 200704;     // 50001*4 (padded)
  int* cursor = (int*)ws;          ws += 200192;     // 50000*4 (padded)
  int* bsum = (int*)ws;            ws += 1024;       // 196*4 (padded)
  int* boff = (int*)ws;            ws += 1024;       // 256*4
  int* csr = (int*)ws;             ws += 3200000;    // 800000*4

  hipMemsetAsync(deg, 0, (size_t)N_NODES * 4, stream);
  cvt_x_kernel<<<12500, 256, 0, stream>>>(x, xbf);
  deg_kernel<<<3125, 256, 0, stream>>>(edst, deg);
  scan_bsum_kernel<<<SCAN_BLOCKS, 256, 0, stream>>>(deg, bsum);
  scan_bscan_kernel<<<1, 256, 0, stream>>>(bsum, boff);
  scan_final_kernel<<<SCAN_BLOCKS, 256, 0, stream>>>(deg, boff, offsets, cursor);
  fill_kernel<<<3125, 256, 0, stream>>>(esrc, edst, cursor, csr);
  agg_kernel<<<12500, 256, 0, stream>>>(xbf, offsets, csr, basebf);
  extract_kernel<<<8, 256, 0, stream>>>(hm, colb, signb);
  build_wct_kernel<<<512, 256, 0, stream>>>(Wpost, Wself, colb, signb, wct);
  gemm_kernel<<<dim3(3128), 256, 0, stream>>>(basebf, xbf, wct, bias, out);
}

// Round 5
// 264.555 us; speedup vs baseline: 1.1997x; 1.0578x over previous
//
#include <hip/hip_runtime.h>
#include <cstdint>

#define N_NODES 50000
#define IN_DIM 256
#define OUT_DIM 512
#define NUM_HASH 8
#define HASH_DIM 256
#define N_EDGES 800000
#define SCAN_BLOCKS ((N_NODES + 255) / 256)  // 196

typedef unsigned short ushort_t;
typedef __attribute__((ext_vector_type(8))) short short8;
typedef __attribute__((ext_vector_type(4))) float f32x4;

__device__ __forceinline__ ushort_t f2bf(float f) {
  uint32_t u = __builtin_bit_cast(uint32_t, f);
  u = (u + 0x7fffu + ((u >> 16) & 1u)) >> 16;
  return (ushort_t)u;
}
__device__ __forceinline__ float bf2f(uint32_t u) {
  return __builtin_bit_cast(float, u << 16);
}

__device__ __forceinline__ void gload_lds16(const void* g, void* l) {
  __builtin_amdgcn_global_load_lds((const __attribute__((address_space(1))) void*)g,
                                   (__attribute__((address_space(3))) void*)l, 16, 0, 0);
}

// ---- convert x (f32) -> x_bf (bf16), 4 elems/thread ----
__global__ void cvt_x_kernel(const float* __restrict__ x, ushort_t* __restrict__ xbf) {
  int g = blockIdx.x * 256 + threadIdx.x;
  float4 v = reinterpret_cast<const float4*>(x)[g];
  uint2 pack;
  pack.x = (uint32_t)f2bf(v.x) | ((uint32_t)f2bf(v.y) << 16);
  pack.y = (uint32_t)f2bf(v.z) | ((uint32_t)f2bf(v.w) << 16);
  *reinterpret_cast<uint2*>(xbf + (size_t)g * 4) = pack;
}

// ---- degree count ----
__global__ void deg_kernel(const int* __restrict__ dst, int* __restrict__ deg) {
  int e = blockIdx.x * 256 + threadIdx.x;
  atomicAdd(&deg[dst[e]], 1);
}

// ---- scan phase 1: per-block (256-elem) sums ----
__global__ void scan_bsum_kernel(const int* __restrict__ deg, int* __restrict__ bsum) {
  __shared__ int ws[4];
  const int t = threadIdx.x;
  const int i = blockIdx.x * 256 + t;
  int v = (i < N_NODES) ? deg[i] : 0;
#pragma unroll
  for (int d = 1; d < 64; d <<= 1) v += __shfl_xor(v, d, 64);
  if ((t & 63) == 0) ws[t >> 6] = v;
  __syncthreads();
  if (t == 0) bsum[blockIdx.x] = ws[0] + ws[1] + ws[2] + ws[3];
}

// ---- scan phase 2: single block exclusive-scans the 196 block sums ----
__global__ void scan_bscan_kernel(const int* __restrict__ bsum, int* __restrict__ boff) {
  __shared__ int tmp[256];
  const int t = threadIdx.x;
  int v = (t < SCAN_BLOCKS) ? bsum[t] : 0;
  tmp[t] = v;
  __syncthreads();
#pragma unroll
  for (int d = 1; d < 256; d <<= 1) {
    int add = (t >= d) ? tmp[t - d] : 0;
    __syncthreads();
    tmp[t] += add;
    __syncthreads();
  }
  boff[t] = (t == 0) ? 0 : tmp[t - 1];
}

// ---- scan phase 3: per-block inclusive scan + base ----
__global__ void scan_final_kernel(const int* __restrict__ deg, const int* __restrict__ boff,
                                  int* __restrict__ offsets, int* __restrict__ cursor) {
  __shared__ int tmp[256];
  const int t = threadIdx.x;
  const int i = blockIdx.x * 256 + t;
  int v = (i < N_NODES) ? deg[i] : 0;
  tmp[t] = v;
  __syncthreads();
#pragma unroll
  for (int d = 1; d < 256; d <<= 1) {
    int add = (t >= d) ? tmp[t - d] : 0;
    __syncthreads();
    tmp[t] += add;
    __syncthreads();
  }
  const int excl = tmp[t] - v + boff[blockIdx.x];
  if (i < N_NODES) {
    offsets[i] = excl;
    cursor[i] = excl;
  }
  if (i == 0) offsets[N_NODES] = N_EDGES;
}

// ---- CSR fill ----
__global__ void fill_kernel(const int* __restrict__ src, const int* __restrict__ dst,
                            int* __restrict__ cursor, int* __restrict__ csr) {
  int e = blockIdx.x * 256 + threadIdx.x;
  int d = dst[e];
  int pos = atomicAdd(&cursor[d], 1);
  csr[pos] = src[e];
}

// ---- segment mean: one wave per node, 2-edge unrolled for MLP ----
__global__ void agg_kernel(const ushort_t* __restrict__ xbf, const int* __restrict__ offsets,
                           const int* __restrict__ csr, ushort_t* __restrict__ basebf) {
  int wid = (blockIdx.x * 256 + threadIdx.x) >> 6;
  int lane = threadIdx.x & 63;
  if (wid >= N_NODES) return;
  int off = offsets[wid], end = offsets[wid + 1];
  float a0 = 0.f, a1 = 0.f, a2 = 0.f, a3 = 0.f;
  float c0 = 0.f, c1 = 0.f, c2 = 0.f, c3 = 0.f;
  int i = off;
  for (; i + 2 <= end; i += 2) {
    int s0 = csr[i], s1 = csr[i + 1];
    uint2 v0 = *reinterpret_cast<const uint2*>(xbf + (size_t)s0 * IN_DIM + lane * 4);
    uint2 v1 = *reinterpret_cast<const uint2*>(xbf + (size_t)s1 * IN_DIM + lane * 4);
    a0 += bf2f(v0.x & 0xffffu);
    a1 += bf2f(v0.x >> 16);
    a2 += bf2f(v0.y & 0xffffu);
    a3 += bf2f(v0.y >> 16);
    c0 += bf2f(v1.x & 0xffffu);
    c1 += bf2f(v1.x >> 16);
    c2 += bf2f(v1.y & 0xffffu);
    c3 += bf2f(v1.y >> 16);
  }
  if (i < end) {
    int s0 = csr[i];
    uint2 v0 = *reinterpret_cast<const uint2*>(xbf + (size_t)s0 * IN_DIM + lane * 4);
    a0 += bf2f(v0.x & 0xffffu);
    a1 += bf2f(v0.x >> 16);
    a2 += bf2f(v0.y & 0xffffu);
    a3 += bf2f(v0.y >> 16);
  }
  a0 += c0; a1 += c1; a2 += c2; a3 += c3;
  int d = end - off;
  if (d > 0) {
    float inv = 1.0f / (float)d;
    a0 *= inv; a1 *= inv; a2 *= inv; a3 *= inv;
  } else {
    uint2 v = *reinterpret_cast<const uint2*>(xbf + (size_t)wid * IN_DIM + lane * 4);
    a0 = bf2f(v.x & 0xffffu);
    a1 = bf2f(v.x >> 16);
    a2 = bf2f(v.y & 0xffffu);
    a3 = bf2f(v.y >> 16);
  }
  uint2 o;
  o.x = (uint32_t)f2bf(a0) | ((uint32_t)f2bf(a1) << 16);
  o.y = (uint32_t)f2bf(a2) | ((uint32_t)f2bf(a3) << 16);
  *reinterpret_cast<uint2*>(basebf + (size_t)wid * IN_DIM + lane * 4) = o;
}

// ---- extract (col, sign) from signed one-hot hash mats ----
__global__ void extract_kernel(const float* __restrict__ hm, int* __restrict__ col,
                               float* __restrict__ sign) {
  const int t = blockIdx.x * 256 + threadIdx.x;  // 2048 = (h,i)
  const float* row = hm + (size_t)t * HASH_DIM;
  int c = 0;
  float s = 0.f;
  for (int j = 0; j < HASH_DIM; ++j) {
    float v = row[j];
    if (v != 0.f) { c = j; s = v; }
  }
  col[t] = c;
  sign[t] = s;
}

// ---- build combined B^T [OUT=512 rows][K=512 cols] bf16 ----
__global__ void build_wct_kernel(const float* __restrict__ Wpost, const float* __restrict__ Wself,
                                 const int* __restrict__ col, const float* __restrict__ sign,
                                 ushort_t* __restrict__ wct) {
  const int k = blockIdx.x;  // 0..511
#pragma unroll
  for (int t = 0; t < 2; ++t) {
    const int o = threadIdx.x + t * 256;
    float acc;
    if (k < 256) {
      acc = 0.f;
      for (int h = 0; h < NUM_HASH; ++h) {
        const int c = col[h * 256 + k];
        const float s = sign[h * 256 + k];
        acc += s * Wpost[(size_t)(h * 256 + c) * OUT_DIM + o];
      }
    } else {
      acc = Wself[(size_t)(k - 256) * OUT_DIM + o];
    }
    wct[(size_t)o * 512 + k] = f2bf(acc);
  }
}

// ---- fused GEMM: out = elu([base|x] @ [Weff;Wself] + bias) ----
// Barrier-free K-loop: block (8 waves) owns BN=64 cols; full B column-panel
// [16 kt][4 kslot][64 col][8] = 64KB loaded into LDS ONCE (one barrier),
// then each wave independently computes 32 rows x 64 cols over K=512 with
// A fragments loaded global->VGPR directly (natural MFMA A gather). No
// per-kt barriers -> no vmcnt(0) drain -> compiler pipelines loads freely.
// Grid 196 bm x 8 bn, XCD-chunked so a bm stripe's 8 bn-siblings share L2.
__global__ __launch_bounds__(512, 4) void gemm_kernel(const ushort_t* __restrict__ Abase,
                                                      const ushort_t* __restrict__ Ax,
                                                      const ushort_t* __restrict__ Bt,
                                                      const float* __restrict__ bias,
                                                      float* __restrict__ out) {
  __shared__ __align__(16) ushort_t Bs[32768];  // 64KB: [kt 16][sl 4][col 64][8]
  const int tid = threadIdx.x;
  const int lane = tid & 63;
  const int w = tid >> 6;
  const int fid = blockIdx.x;
  const int l = (fid & 7) * SCAN_BLOCKS + (fid >> 3);  // 1568 = 8*196
  const int bm = l >> 3, bn = l & 7;
  const int n0 = bn * 64;

  // stage full B panel: 8 x 16B per thread, dest linear in tid
#pragma unroll
  for (int j = 0; j < 8; ++j) {
    const int c = j * 512 + tid;        // 0..4095
    const int kt_s = c >> 8;            // /256
    const int r8 = c & 255;
    const int sl_s = r8 >> 6;
    const int col_s = r8 & 63;
    gload_lds16(Bt + (size_t)(n0 + col_s) * 512 + kt_s * 32 + sl_s * 8, &Bs[c * 8]);
  }
  __syncthreads();

  const int r0 = bm * 256 + w * 32;
  if (r0 >= N_NODES) return;

  const int fr = lane & 15, sl = lane >> 4;
  f32x4 acc[2][4] = {};

  for (int kt = 0; kt < 16; ++kt) {
    const ushort_t* Aptr = (kt < 8) ? Abase : Ax;
    const int k0 = (kt & 7) * 32;
    short8 af[2];
#pragma unroll
    for (int i = 0; i < 2; ++i) {
      int rg = r0 + i * 16 + fr;
      rg = rg < N_NODES ? rg : N_NODES - 1;
      af[i] = *reinterpret_cast<const short8*>(Aptr + (size_t)rg * IN_DIM + k0 + sl * 8);
    }
    short8 bf[4];
#pragma unroll
    for (int j = 0; j < 4; ++j)
      bf[j] = *reinterpret_cast<const short8*>(&Bs[((kt * 4 + sl) * 64 + j * 16 + fr) * 8]);
#pragma unroll
    for (int i = 0; i < 2; ++i)
#pragma unroll
      for (int j = 0; j < 4; ++j)
        acc[i][j] = __builtin_amdgcn_mfma_f32_16x16x32_bf16(af[i], bf[j], acc[i][j], 0, 0, 0);
  }

#pragma unroll
  for (int j = 0; j < 4; ++j) {
    const int colg = n0 + j * 16 + fr;
    const float b = bias[colg];
#pragma unroll
    for (int i = 0; i < 2; ++i) {
#pragma unroll
      for (int r = 0; r < 4; ++r) {
        const int rowg = r0 + i * 16 + sl * 4 + r;
        if (rowg < N_NODES) {
          float v = acc[i][j][r] + b;
          out[(size_t)rowg * OUT_DIM + colg] = v > 0.f ? (__expf(v), v) : __expf(v) - 1.0f;
        }
      }
    }
  }
}

extern "C" void kernel_launch(void* const* d_in, const int* in_sizes, int n_in,
                              void* d_out, int out_size, void* d_ws, size_t ws_size,
                              hipStream_t stream) {
  const float* x = (const float*)d_in[0];
  const float* Wpost = (const float*)d_in[1];
  const float* Wself = (const float*)d_in[2];
  const float* bias = (const float*)d_in[3];
  const float* hm = (const float*)d_in[4];
  const int* esrc = (const int*)d_in[5];
  const int* edst = (const int*)d_in[6];
  float* out = (float*)d_out;

  char* ws = (char*)d_ws;
  ushort_t* xbf = (ushort_t*)ws;   ws += 25600000;   // 50000*256*2
  ushort_t* basebf = (ushort_t*)ws; ws += 25600000;  // 50000*256*2
  ushort_t* wct = (ushort_t*)ws;   ws += 524288;     // 512*512*2
  int* colb = (int*)ws;            ws += 8192;       // 2048*4
  float* signb = (float*)ws;       ws += 8192;       // 2048*4
  int* deg = (int*)ws;             ws += 200192;     // 50000*4 (padded)
  int* offsets = (int*)ws;         ws += 200704;     // 50001*4 (padded)
  int* cursor = (int*)ws;          ws += 200192;     // 50000*4 (padded)
  int* bsum = (int*)ws;            ws += 1024;       // 196*4 (padded)
  int* boff = (int*)ws;            ws += 1024;       // 256*4
  int* csr = (int*)ws;             ws += 3200000;    // 800000*4

  hipMemsetAsync(deg, 0, (size_t)N_NODES * 4, stream);
  cvt_x_kernel<<<12500, 256, 0, stream>>>(x, xbf);
  deg_kernel<<<3125, 256, 0, stream>>>(edst, deg);
  scan_bsum_kernel<<<SCAN_BLOCKS, 256, 0, stream>>>(deg, bsum);
  scan_bscan_kernel<<<1, 256, 0, stream>>>(bsum, boff);
  scan_final_kernel<<<SCAN_BLOCKS, 256, 0, stream>>>(deg, boff, offsets, cursor);
  fill_kernel<<<3125, 256, 0, stream>>>(esrc, edst, cursor, csr);
  agg_kernel<<<12500, 256, 0, stream>>>(xbf, offsets, csr, basebf);
  extract_kernel<<<8, 256, 0, stream>>>(hm, colb, signb);
  build_wct_kernel<<<512, 256, 0, stream>>>(Wpost, Wself, colb, signb, wct);
  gemm_kernel<<<dim3(8 * SCAN_BLOCKS), 512, 0, stream>>>(basebf, xbf, wct, bias, out);
}

// Round 6
// 254.721 us; speedup vs baseline: 1.2461x; 1.0386x over previous
//
#include <hip/hip_runtime.h>
#include <cstdint>

#define N_NODES 50000
#define IN_DIM 256
#define OUT_DIM 512
#define NUM_HASH 8
#define HASH_DIM 256
#define N_EDGES 800000
#define SCAN_BLOCKS ((N_NODES + 255) / 256)  // 196
#define A2_RT (N_NODES / 16)                 // 3125

typedef unsigned short ushort_t;
typedef __attribute__((ext_vector_type(8))) short short8;
typedef __attribute__((ext_vector_type(4))) float f32x4;

__device__ __forceinline__ ushort_t f2bf(float f) {
  uint32_t u = __builtin_bit_cast(uint32_t, f);
  u = (u + 0x7fffu + ((u >> 16) & 1u)) >> 16;
  return (ushort_t)u;
}
__device__ __forceinline__ float bf2f(uint32_t u) {
  return __builtin_bit_cast(float, u << 16);
}

__device__ __forceinline__ void gload_lds16(const void* g, void* l) {
  __builtin_amdgcn_global_load_lds((const __attribute__((address_space(1))) void*)g,
                                   (__attribute__((address_space(3))) void*)l, 16, 0, 0);
}

// fragment-layout element offset for row r, k-chunk owned by sub-lane l (l=k/4
// within the row's 64 4-elem chunks); base kt offset ktbase (0 or 8).
// A2 element index = ((rt*16 + kt)*64 + sl*16 + fr)*8 + e
__device__ __forceinline__ size_t frag_off(int r, int l, int ktbase) {
  const int rt = r >> 4, fr = r & 15;
  const int kt = ktbase + (l >> 3);
  const int sl = (l >> 1) & 3;
  return ((size_t)(rt * 16 + kt) * 64 + sl * 16 + fr) * 8 + (l & 1) * 4;
}

// ---- convert x (f32): frag layout (kt 8..15) always; row-major bf16 optional ----
__global__ void cvt_x_kernel(const float* __restrict__ x, ushort_t* __restrict__ A2,
                             ushort_t* __restrict__ xbf, int use_bf) {
  int g = blockIdx.x * 256 + threadIdx.x;  // 3.2M threads, 4 floats each
  float4 v = reinterpret_cast<const float4*>(x)[g];
  uint2 pack;
  pack.x = (uint32_t)f2bf(v.x) | ((uint32_t)f2bf(v.y) << 16);
  pack.y = (uint32_t)f2bf(v.z) | ((uint32_t)f2bf(v.w) << 16);
  const int r = g >> 6, l = g & 63;
  *reinterpret_cast<uint2*>(A2 + frag_off(r, l, 8)) = pack;
  if (use_bf) *reinterpret_cast<uint2*>(xbf + (size_t)g * 4) = pack;
}

// ---- degree count ----
__global__ void deg_kernel(const int* __restrict__ dst, int* __restrict__ deg) {
  int e = blockIdx.x * 256 + threadIdx.x;
  atomicAdd(&deg[dst[e]], 1);
}

// ---- scan phase 1: per-block (256-elem) sums ----
__global__ void scan_bsum_kernel(const int* __restrict__ deg, int* __restrict__ bsum) {
  __shared__ int ws[4];
  const int t = threadIdx.x;
  const int i = blockIdx.x * 256 + t;
  int v = (i < N_NODES) ? deg[i] : 0;
#pragma unroll
  for (int d = 1; d < 64; d <<= 1) v += __shfl_xor(v, d, 64);
  if ((t & 63) == 0) ws[t >> 6] = v;
  __syncthreads();
  if (t == 0) bsum[blockIdx.x] = ws[0] + ws[1] + ws[2] + ws[3];
}

// ---- scan phase 2: single block exclusive-scans the 196 block sums ----
__global__ void scan_bscan_kernel(const int* __restrict__ bsum, int* __restrict__ boff) {
  __shared__ int tmp[256];
  const int t = threadIdx.x;
  int v = (t < SCAN_BLOCKS) ? bsum[t] : 0;
  tmp[t] = v;
  __syncthreads();
#pragma unroll
  for (int d = 1; d < 256; d <<= 1) {
    int add = (t >= d) ? tmp[t - d] : 0;
    __syncthreads();
    tmp[t] += add;
    __syncthreads();
  }
  boff[t] = (t == 0) ? 0 : tmp[t - 1];
}

// ---- scan phase 3: per-block inclusive scan + base ----
__global__ void scan_final_kernel(const int* __restrict__ deg, const int* __restrict__ boff,
                                  int* __restrict__ offsets, int* __restrict__ cursor) {
  __shared__ int tmp[256];
  const int t = threadIdx.x;
  const int i = blockIdx.x * 256 + t;
  int v = (i < N_NODES) ? deg[i] : 0;
  tmp[t] = v;
  __syncthreads();
#pragma unroll
  for (int d = 1; d < 256; d <<= 1) {
    int add = (t >= d) ? tmp[t - d] : 0;
    __syncthreads();
    tmp[t] += add;
    __syncthreads();
  }
  const int excl = tmp[t] - v + boff[blockIdx.x];
  if (i < N_NODES) {
    offsets[i] = excl;
    cursor[i] = excl;
  }
  if (i == 0) offsets[N_NODES] = N_EDGES;
}

// ---- CSR fill ----
__global__ void fill_kernel(const int* __restrict__ src, const int* __restrict__ dst,
                            int* __restrict__ cursor, int* __restrict__ csr) {
  int e = blockIdx.x * 256 + threadIdx.x;
  int d = dst[e];
  int pos = atomicAdd(&cursor[d], 1);
  csr[pos] = src[e];
}

// ---- segment mean: one wave per node, 2-edge unrolled; writes frag layout ----
__global__ void agg_kernel(const float* __restrict__ xf, const ushort_t* __restrict__ xbf,
                           int use_bf, const int* __restrict__ offsets,
                           const int* __restrict__ csr, ushort_t* __restrict__ A2) {
  int wid = (blockIdx.x * 256 + threadIdx.x) >> 6;
  int lane = threadIdx.x & 63;
  if (wid >= N_NODES) return;
  int off = offsets[wid], end = offsets[wid + 1];
  float a0 = 0.f, a1 = 0.f, a2 = 0.f, a3 = 0.f;
  float c0 = 0.f, c1 = 0.f, c2 = 0.f, c3 = 0.f;
  if (use_bf) {
    int i = off;
    for (; i + 2 <= end; i += 2) {
      int s0 = csr[i], s1 = csr[i + 1];
      uint2 v0 = *reinterpret_cast<const uint2*>(xbf + (size_t)s0 * IN_DIM + lane * 4);
      uint2 v1 = *reinterpret_cast<const uint2*>(xbf + (size_t)s1 * IN_DIM + lane * 4);
      a0 += bf2f(v0.x & 0xffffu);
      a1 += bf2f(v0.x >> 16);
      a2 += bf2f(v0.y & 0xffffu);
      a3 += bf2f(v0.y >> 16);
      c0 += bf2f(v1.x & 0xffffu);
      c1 += bf2f(v1.x >> 16);
      c2 += bf2f(v1.y & 0xffffu);
      c3 += bf2f(v1.y >> 16);
    }
    if (i < end) {
      int s0 = csr[i];
      uint2 v0 = *reinterpret_cast<const uint2*>(xbf + (size_t)s0 * IN_DIM + lane * 4);
      a0 += bf2f(v0.x & 0xffffu);
      a1 += bf2f(v0.x >> 16);
      a2 += bf2f(v0.y & 0xffffu);
      a3 += bf2f(v0.y >> 16);
    }
    a0 += c0; a1 += c1; a2 += c2; a3 += c3;
  } else {
    int i = off;
    for (; i + 2 <= end; i += 2) {
      int s0 = csr[i], s1 = csr[i + 1];
      float4 v0 = *reinterpret_cast<const float4*>(xf + (size_t)s0 * IN_DIM + lane * 4);
      float4 v1 = *reinterpret_cast<const float4*>(xf + (size_t)s1 * IN_DIM + lane * 4);
      a0 += v0.x; a1 += v0.y; a2 += v0.z; a3 += v0.w;
      c0 += v1.x; c1 += v1.y; c2 += v1.z; c3 += v1.w;
    }
    if (i < end) {
      float4 v0 = *reinterpret_cast<const float4*>(xf + (size_t)csr[i] * IN_DIM + lane * 4);
      a0 += v0.x; a1 += v0.y; a2 += v0.z; a3 += v0.w;
    }
    a0 += c0; a1 += c1; a2 += c2; a3 += c3;
  }
  int d = end - off;
  if (d > 0) {
    float inv = 1.0f / (float)d;
    a0 *= inv; a1 *= inv; a2 *= inv; a3 *= inv;
  } else {
    float4 v = *reinterpret_cast<const float4*>(xf + (size_t)wid * IN_DIM + lane * 4);
    a0 = v.x; a1 = v.y; a2 = v.z; a3 = v.w;
  }
  uint2 o;
  o.x = (uint32_t)f2bf(a0) | ((uint32_t)f2bf(a1) << 16);
  o.y = (uint32_t)f2bf(a2) | ((uint32_t)f2bf(a3) << 16);
  *reinterpret_cast<uint2*>(A2 + frag_off(wid, lane, 0)) = o;
}

// ---- extract (col, sign) from signed one-hot hash mats ----
__global__ void extract_kernel(const float* __restrict__ hm, int* __restrict__ col,
                               float* __restrict__ sign) {
  const int t = blockIdx.x * 256 + threadIdx.x;  // 2048 = (h,i)
  const float* row = hm + (size_t)t * HASH_DIM;
  int c = 0;
  float s = 0.f;
  for (int j = 0; j < HASH_DIM; ++j) {
    float v = row[j];
    if (v != 0.f) { c = j; s = v; }
  }
  col[t] = c;
  sign[t] = s;
}

// ---- build combined B^T [OUT=512 rows][K=512 cols] bf16 ----
__global__ void build_wct_kernel(const float* __restrict__ Wpost, const float* __restrict__ Wself,
                                 const int* __restrict__ col, const float* __restrict__ sign,
                                 ushort_t* __restrict__ wct) {
  const int k = blockIdx.x;  // 0..511
#pragma unroll
  for (int t = 0; t < 2; ++t) {
    const int o = threadIdx.x + t * 256;
    float acc;
    if (k < 256) {
      acc = 0.f;
      for (int h = 0; h < NUM_HASH; ++h) {
        const int c = col[h * 256 + k];
        const float s = sign[h * 256 + k];
        acc += s * Wpost[(size_t)(h * 256 + c) * OUT_DIM + o];
      }
    } else {
      acc = Wself[(size_t)(k - 256) * OUT_DIM + o];
    }
    wct[(size_t)o * 512 + k] = f2bf(acc);
  }
}

// ---- fused GEMM: out = elu(A @ [Weff;Wself] + bias) ----
// Barrier-free K-loop; B panel (64 cols x 512 K = 64KB) in LDS once.
// A is pre-packed in MFMA fragment-major layout -> each A-fragment load is
// one contiguous 1KB wave-load (lane*16B), manually prefetched 1 kt ahead.
__global__ __launch_bounds__(512, 4) void gemm_kernel(const ushort_t* __restrict__ A2,
                                                      const ushort_t* __restrict__ Bt,
                                                      const float* __restrict__ bias,
                                                      float* __restrict__ out) {
  __shared__ __align__(16) ushort_t Bs[32768];  // 64KB: [kt 16][sl 4][col 64][8]
  const int tid = threadIdx.x;
  const int lane = tid & 63;
  const int w = tid >> 6;
  const int fid = blockIdx.x;
  const int l = (fid & 7) * SCAN_BLOCKS + (fid >> 3);  // 1568 = 8*196
  const int bm = l >> 3, bn = l & 7;
  const int n0 = bn * 64;

  // stage full B panel: 8 x 16B per thread, dest linear in tid
#pragma unroll
  for (int j = 0; j < 8; ++j) {
    const int c = j * 512 + tid;        // 0..4095
    const int kt_s = c >> 8;
    const int r8 = c & 255;
    const int sl_s = r8 >> 6;
    const int col_s = r8 & 63;
    gload_lds16(Bt + (size_t)(n0 + col_s) * 512 + kt_s * 32 + sl_s * 8, &Bs[c * 8]);
  }
  __syncthreads();

  const int r0 = bm * 256 + w * 32;
  if (r0 >= N_NODES) return;
  const int rta = min(bm * 16 + w * 2, A2_RT - 1);
  const int rtb = min(bm * 16 + w * 2 + 1, A2_RT - 1);

  const int fr = lane & 15, sl = lane >> 4;
  f32x4 acc[2][4] = {};

  short8 pa, pb;
  pa = *reinterpret_cast<const short8*>(A2 + (size_t)(rta * 16 + 0) * 512 + lane * 8);
  pb = *reinterpret_cast<const short8*>(A2 + (size_t)(rtb * 16 + 0) * 512 + lane * 8);
#pragma unroll
  for (int kt = 0; kt < 16; ++kt) {
    const short8 a0 = pa, a1 = pb;
    if (kt < 15) {
      pa = *reinterpret_cast<const short8*>(A2 + (size_t)(rta * 16 + kt + 1) * 512 + lane * 8);
      pb = *reinterpret_cast<const short8*>(A2 + (size_t)(rtb * 16 + kt + 1) * 512 + lane * 8);
    }
    short8 bf[4];
#pragma unroll
    for (int j = 0; j < 4; ++j)
      bf[j] = *reinterpret_cast<const short8*>(&Bs[((kt * 4 + sl) * 64 + j * 16 + fr) * 8]);
#pragma unroll
    for (int j = 0; j < 4; ++j) {
      acc[0][j] = __builtin_amdgcn_mfma_f32_16x16x32_bf16(a0, bf[j], acc[0][j], 0, 0, 0);
      acc[1][j] = __builtin_amdgcn_mfma_f32_16x16x32_bf16(a1, bf[j], acc[1][j], 0, 0, 0);
    }
  }

#pragma unroll
  for (int j = 0; j < 4; ++j) {
    const int colg = n0 + j * 16 + fr;
    const float b = bias[colg];
#pragma unroll
    for (int i = 0; i < 2; ++i) {
#pragma unroll
      for (int r = 0; r < 4; ++r) {
        const int rowg = r0 + i * 16 + sl * 4 + r;
        if (rowg < N_NODES) {
          float v = acc[i][j][r] + b;
          out[(size_t)rowg * OUT_DIM + colg] = v > 0.f ? v : __expf(v) - 1.0f;
        }
      }
    }
  }
}

extern "C" void kernel_launch(void* const* d_in, const int* in_sizes, int n_in,
                              void* d_out, int out_size, void* d_ws, size_t ws_size,
                              hipStream_t stream) {
  const float* x = (const float*)d_in[0];
  const float* Wpost = (const float*)d_in[1];
  const float* Wself = (const float*)d_in[2];
  const float* bias = (const float*)d_in[3];
  const float* hm = (const float*)d_in[4];
  const int* esrc = (const int*)d_in[5];
  const int* edst = (const int*)d_in[6];
  float* out = (float*)d_out;

  char* ws = (char*)d_ws;
  ushort_t* A2 = (ushort_t*)ws;    ws += 51200000;   // 3125*16*64*8*2 frag-layout A
  ushort_t* wct = (ushort_t*)ws;   ws += 524288;     // 512*512*2
  int* colb = (int*)ws;            ws += 8192;
  float* signb = (float*)ws;       ws += 8192;
  int* deg = (int*)ws;             ws += 200192;
  int* offsets = (int*)ws;         ws += 200704;
  int* cursor = (int*)ws;          ws += 200192;
  int* bsum = (int*)ws;            ws += 1024;
  int* boff = (int*)ws;            ws += 1024;
  int* csr = (int*)ws;             ws += 3200000;
  const size_t base_need = (size_t)(ws - (char*)d_ws);
  const int use_bf = (ws_size >= base_need + 25600000) ? 1 : 0;
  ushort_t* xbf = (ushort_t*)ws;   // 25600000 bytes, only if use_bf

  hipMemsetAsync(deg, 0, (size_t)N_NODES * 4, stream);
  cvt_x_kernel<<<12500, 256, 0, stream>>>(x, A2, xbf, use_bf);
  deg_kernel<<<3125, 256, 0, stream>>>(edst, deg);
  scan_bsum_kernel<<<SCAN_BLOCKS, 256, 0, stream>>>(deg, bsum);
  scan_bscan_kernel<<<1, 256, 0, stream>>>(bsum, boff);
  scan_final_kernel<<<SCAN_BLOCKS, 256, 0, stream>>>(deg, boff, offsets, cursor);
  fill_kernel<<<3125, 256, 0, stream>>>(esrc, edst, cursor, csr);
  agg_kernel<<<12500, 256, 0, stream>>>(x, xbf, use_bf, offsets, csr, A2);
  extract_kernel<<<8, 256, 0, stream>>>(hm, colb, signb);
  build_wct_kernel<<<512, 256, 0, stream>>>(Wpost, Wself, colb, signb, wct);
  gemm_kernel<<<dim3(8 * SCAN_BLOCKS), 512, 0, stream>>>(A2, wct, bias, out);
}

// Round 7
// 245.468 us; speedup vs baseline: 1.2930x; 1.0377x over previous
//
#include <hip/hip_runtime.h>
#include <cstdint>

#define N_NODES 50000
#define IN_DIM 256
#define OUT_DIM 512
#define NUM_HASH 8
#define HASH_DIM 256
#define N_EDGES 800000
#define SCAN_BLOCKS ((N_NODES + 255) / 256)  // 196
#define A2_RT (N_NODES / 16)                 // 3125

typedef unsigned short ushort_t;
typedef __attribute__((ext_vector_type(8))) short short8;
typedef __attribute__((ext_vector_type(4))) float f32x4;

__device__ __forceinline__ ushort_t f2bf(float f) {
  uint32_t u = __builtin_bit_cast(uint32_t, f);
  u = (u + 0x7fffu + ((u >> 16) & 1u)) >> 16;
  return (ushort_t)u;
}
__device__ __forceinline__ float bf2f(uint32_t u) {
  return __builtin_bit_cast(float, u << 16);
}

__device__ __forceinline__ void gload_lds16(const void* g, void* l) {
  __builtin_amdgcn_global_load_lds((const __attribute__((address_space(1))) void*)g,
                                   (__attribute__((address_space(3))) void*)l, 16, 0, 0);
}

// fragment-layout element offset for row r, sub-lane l (l = k/4 chunk id).
// A2 element index = ((rt*16 + kt)*64 + sl*16 + fr)*8 + e
__device__ __forceinline__ size_t frag_off(int r, int l, int ktbase) {
  const int rt = r >> 4, fr = r & 15;
  const int kt = ktbase + (l >> 3);
  const int sl = (l >> 1) & 3;
  return ((size_t)(rt * 16 + kt) * 64 + sl * 16 + fr) * 8 + (l & 1) * 4;
}

// ---- convert x (f32): frag layout (kt 8..15) always; row-major bf16 optional ----
__global__ void cvt_x_kernel(const float* __restrict__ x, ushort_t* __restrict__ A2,
                             ushort_t* __restrict__ xbf, int use_bf) {
  int g = blockIdx.x * 256 + threadIdx.x;  // 3.2M threads, 4 floats each
  float4 v = reinterpret_cast<const float4*>(x)[g];
  uint2 pack;
  pack.x = (uint32_t)f2bf(v.x) | ((uint32_t)f2bf(v.y) << 16);
  pack.y = (uint32_t)f2bf(v.z) | ((uint32_t)f2bf(v.w) << 16);
  const int r = g >> 6, l = g & 63;
  *reinterpret_cast<uint2*>(A2 + frag_off(r, l, 8)) = pack;
  if (use_bf) *reinterpret_cast<uint2*>(xbf + (size_t)g * 4) = pack;
}

// ---- degree count ----
__global__ void deg_kernel(const int* __restrict__ dst, int* __restrict__ deg) {
  int e = blockIdx.x * 256 + threadIdx.x;
  atomicAdd(&deg[dst[e]], 1);
}

// ---- scan phase 1: per-block (256-elem) sums ----
__global__ void scan_bsum_kernel(const int* __restrict__ deg, int* __restrict__ bsum) {
  __shared__ int ws[4];
  const int t = threadIdx.x;
  const int i = blockIdx.x * 256 + t;
  int v = (i < N_NODES) ? deg[i] : 0;
#pragma unroll
  for (int d = 1; d < 64; d <<= 1) v += __shfl_xor(v, d, 64);
  if ((t & 63) == 0) ws[t >> 6] = v;
  __syncthreads();
  if (t == 0) bsum[blockIdx.x] = ws[0] + ws[1] + ws[2] + ws[3];
}

// ---- scan phase 2: single block exclusive-scans the 196 block sums ----
__global__ void scan_bscan_kernel(const int* __restrict__ bsum, int* __restrict__ boff) {
  __shared__ int tmp[256];
  const int t = threadIdx.x;
  int v = (t < SCAN_BLOCKS) ? bsum[t] : 0;
  tmp[t] = v;
  __syncthreads();
#pragma unroll
  for (int d = 1; d < 256; d <<= 1) {
    int add = (t >= d) ? tmp[t - d] : 0;
    __syncthreads();
    tmp[t] += add;
    __syncthreads();
  }
  boff[t] = (t == 0) ? 0 : tmp[t - 1];
}

// ---- scan phase 3: per-block inclusive scan + base ----
__global__ void scan_final_kernel(const int* __restrict__ deg, const int* __restrict__ boff,
                                  int* __restrict__ offsets, int* __restrict__ cursor) {
  __shared__ int tmp[256];
  const int t = threadIdx.x;
  const int i = blockIdx.x * 256 + t;
  int v = (i < N_NODES) ? deg[i] : 0;
  tmp[t] = v;
  __syncthreads();
#pragma unroll
  for (int d = 1; d < 256; d <<= 1) {
    int add = (t >= d) ? tmp[t - d] : 0;
    __syncthreads();
    tmp[t] += add;
    __syncthreads();
  }
  const int excl = tmp[t] - v + boff[blockIdx.x];
  if (i < N_NODES) {
    offsets[i] = excl;
    cursor[i] = excl;
  }
  if (i == 0) offsets[N_NODES] = N_EDGES;
}

// ---- CSR fill ----
__global__ void fill_kernel(const int* __restrict__ src, const int* __restrict__ dst,
                            int* __restrict__ cursor, int* __restrict__ csr) {
  int e = blockIdx.x * 256 + threadIdx.x;
  int d = dst[e];
  int pos = atomicAdd(&cursor[d], 1);
  csr[pos] = src[e];
}

// ---- segment mean: one wave per node, 4-deep edge unroll (MLP=4) ----
__global__ void agg_kernel(const float* __restrict__ xf, const ushort_t* __restrict__ xbf,
                           int use_bf, const int* __restrict__ offsets,
                           const int* __restrict__ csr, ushort_t* __restrict__ A2) {
  int wid = (blockIdx.x * 256 + threadIdx.x) >> 6;
  int lane = threadIdx.x & 63;
  if (wid >= N_NODES) return;
  int off = offsets[wid], end = offsets[wid + 1];
  float a0 = 0.f, a1 = 0.f, a2 = 0.f, a3 = 0.f;
  float c0 = 0.f, c1 = 0.f, c2 = 0.f, c3 = 0.f;
  float e0 = 0.f, e1 = 0.f, e2 = 0.f, e3 = 0.f;
  float g0 = 0.f, g1 = 0.f, g2 = 0.f, g3 = 0.f;
  if (use_bf) {
    int i = off;
    for (; i + 4 <= end; i += 4) {
      int s0 = csr[i], s1 = csr[i + 1], s2 = csr[i + 2], s3 = csr[i + 3];
      uint2 v0 = *reinterpret_cast<const uint2*>(xbf + (size_t)s0 * IN_DIM + lane * 4);
      uint2 v1 = *reinterpret_cast<const uint2*>(xbf + (size_t)s1 * IN_DIM + lane * 4);
      uint2 v2 = *reinterpret_cast<const uint2*>(xbf + (size_t)s2 * IN_DIM + lane * 4);
      uint2 v3 = *reinterpret_cast<const uint2*>(xbf + (size_t)s3 * IN_DIM + lane * 4);
      a0 += bf2f(v0.x & 0xffffu);
      a1 += bf2f(v0.x >> 16);
      a2 += bf2f(v0.y & 0xffffu);
      a3 += bf2f(v0.y >> 16);
      c0 += bf2f(v1.x & 0xffffu);
      c1 += bf2f(v1.x >> 16);
      c2 += bf2f(v1.y & 0xffffu);
      c3 += bf2f(v1.y >> 16);
      e0 += bf2f(v2.x & 0xffffu);
      e1 += bf2f(v2.x >> 16);
      e2 += bf2f(v2.y & 0xffffu);
      e3 += bf2f(v2.y >> 16);
      g0 += bf2f(v3.x & 0xffffu);
      g1 += bf2f(v3.x >> 16);
      g2 += bf2f(v3.y & 0xffffu);
      g3 += bf2f(v3.y >> 16);
    }
    for (; i < end; ++i) {
      int s0 = csr[i];
      uint2 v0 = *reinterpret_cast<const uint2*>(xbf + (size_t)s0 * IN_DIM + lane * 4);
      a0 += bf2f(v0.x & 0xffffu);
      a1 += bf2f(v0.x >> 16);
      a2 += bf2f(v0.y & 0xffffu);
      a3 += bf2f(v0.y >> 16);
    }
    a0 += c0 + e0 + g0;
    a1 += c1 + e1 + g1;
    a2 += c2 + e2 + g2;
    a3 += c3 + e3 + g3;
  } else {
    int i = off;
    for (; i + 2 <= end; i += 2) {
      int s0 = csr[i], s1 = csr[i + 1];
      float4 v0 = *reinterpret_cast<const float4*>(xf + (size_t)s0 * IN_DIM + lane * 4);
      float4 v1 = *reinterpret_cast<const float4*>(xf + (size_t)s1 * IN_DIM + lane * 4);
      a0 += v0.x; a1 += v0.y; a2 += v0.z; a3 += v0.w;
      c0 += v1.x; c1 += v1.y; c2 += v1.z; c3 += v1.w;
    }
    if (i < end) {
      float4 v0 = *reinterpret_cast<const float4*>(xf + (size_t)csr[i] * IN_DIM + lane * 4);
      a0 += v0.x; a1 += v0.y; a2 += v0.z; a3 += v0.w;
    }
    a0 += c0; a1 += c1; a2 += c2; a3 += c3;
  }
  int d = end - off;
  if (d > 0) {
    float inv = 1.0f / (float)d;
    a0 *= inv; a1 *= inv; a2 *= inv; a3 *= inv;
  } else {
    float4 v = *reinterpret_cast<const float4*>(xf + (size_t)wid * IN_DIM + lane * 4);
    a0 = v.x; a1 = v.y; a2 = v.z; a3 = v.w;
  }
  uint2 o;
  o.x = (uint32_t)f2bf(a0) | ((uint32_t)f2bf(a1) << 16);
  o.y = (uint32_t)f2bf(a2) | ((uint32_t)f2bf(a3) << 16);
  *reinterpret_cast<uint2*>(A2 + frag_off(wid, lane, 0)) = o;
}

// ---- extract (col, sign) from signed one-hot hash mats ----
__global__ void extract_kernel(const float* __restrict__ hm, int* __restrict__ col,
                               float* __restrict__ sign) {
  const int t = blockIdx.x * 256 + threadIdx.x;  // 2048 = (h,i)
  const float* row = hm + (size_t)t * HASH_DIM;
  int c = 0;
  float s = 0.f;
  for (int j = 0; j < HASH_DIM; ++j) {
    float v = row[j];
    if (v != 0.f) { c = j; s = v; }
  }
  col[t] = c;
  sign[t] = s;
}

// ---- build combined B^T [OUT=512 rows][K=512 cols] bf16 ----
__global__ void build_wct_kernel(const float* __restrict__ Wpost, const float* __restrict__ Wself,
                                 const int* __restrict__ col, const float* __restrict__ sign,
                                 ushort_t* __restrict__ wct) {
  const int k = blockIdx.x;  // 0..511
#pragma unroll
  for (int t = 0; t < 2; ++t) {
    const int o = threadIdx.x + t * 256;
    float acc;
    if (k < 256) {
      acc = 0.f;
      for (int h = 0; h < NUM_HASH; ++h) {
        const int c = col[h * 256 + k];
        const float s = sign[h * 256 + k];
        acc += s * Wpost[(size_t)(h * 256 + c) * OUT_DIM + o];
      }
    } else {
      acc = Wself[(size_t)(k - 256) * OUT_DIM + o];
    }
    wct[(size_t)o * 512 + k] = f2bf(acc);
  }
}

// ---- fused GEMM: out = elu(A @ [Weff;Wself] + bias) ----
// Barrier-free K-loop; B panel (64 cols x 512 K = 64KB) in LDS once.
// A pre-packed fragment-major -> one contiguous 1KB wave-load per fragment,
// manually prefetched 1 kt ahead.
__global__ __launch_bounds__(512, 4) void gemm_kernel(const ushort_t* __restrict__ A2,
                                                      const ushort_t* __restrict__ Bt,
                                                      const float* __restrict__ bias,
                                                      float* __restrict__ out) {
  __shared__ __align__(16) ushort_t Bs[32768];  // 64KB: [kt 16][sl 4][col 64][8]
  const int tid = threadIdx.x;
  const int lane = tid & 63;
  const int w = tid >> 6;
  const int fid = blockIdx.x;
  const int l = (fid & 7) * SCAN_BLOCKS + (fid >> 3);  // 1568 = 8*196
  const int bm = l >> 3, bn = l & 7;
  const int n0 = bn * 64;

#pragma unroll
  for (int j = 0; j < 8; ++j) {
    const int c = j * 512 + tid;
    const int kt_s = c >> 8;
    const int r8 = c & 255;
    const int sl_s = r8 >> 6;
    const int col_s = r8 & 63;
    gload_lds16(Bt + (size_t)(n0 + col_s) * 512 + kt_s * 32 + sl_s * 8, &Bs[c * 8]);
  }
  __syncthreads();

  const int r0 = bm * 256 + w * 32;
  if (r0 >= N_NODES) return;
  const int rta = min(bm * 16 + w * 2, A2_RT - 1);
  const int rtb = min(bm * 16 + w * 2 + 1, A2_RT - 1);

  const int fr = lane & 15, sl = lane >> 4;
  f32x4 acc[2][4] = {};

  short8 pa, pb;
  pa = *reinterpret_cast<const short8*>(A2 + (size_t)(rta * 16 + 0) * 512 + lane * 8);
  pb = *reinterpret_cast<const short8*>(A2 + (size_t)(rtb * 16 + 0) * 512 + lane * 8);
#pragma unroll
  for (int kt = 0; kt < 16; ++kt) {
    const short8 a0 = pa, a1 = pb;
    if (kt < 15) {
      pa = *reinterpret_cast<const short8*>(A2 + (size_t)(rta * 16 + kt + 1) * 512 + lane * 8);
      pb = *reinterpret_cast<const short8*>(A2 + (size_t)(rtb * 16 + kt + 1) * 512 + lane * 8);
    }
    short8 bf[4];
#pragma unroll
    for (int j = 0; j < 4; ++j)
      bf[j] = *reinterpret_cast<const short8*>(&Bs[((kt * 4 + sl) * 64 + j * 16 + fr) * 8]);
#pragma unroll
    for (int j = 0; j < 4; ++j) {
      acc[0][j] = __builtin_amdgcn_mfma_f32_16x16x32_bf16(a0, bf[j], acc[0][j], 0, 0, 0);
      acc[1][j] = __builtin_amdgcn_mfma_f32_16x16x32_bf16(a1, bf[j], acc[1][j], 0, 0, 0);
    }
  }

#pragma unroll
  for (int j = 0; j < 4; ++j) {
    const int colg = n0 + j * 16 + fr;
    const float b = bias[colg];
#pragma unroll
    for (int i = 0; i < 2; ++i) {
#pragma unroll
      for (int r = 0; r < 4; ++r) {
        const int rowg = r0 + i * 16 + sl * 4 + r;
        if (rowg < N_NODES) {
          float v = acc[i][j][r] + b;
          out[(size_t)rowg * OUT_DIM + colg] = v > 0.f ? v : __expf(v) - 1.0f;
        }
      }
    }
  }
}

extern "C" void kernel_launch(void* const* d_in, const int* in_sizes, int n_in,
                              void* d_out, int out_size, void* d_ws, size_t ws_size,
                              hipStream_t stream) {
  const float* x = (const float*)d_in[0];
  const float* Wpost = (const float*)d_in[1];
  const float* Wself = (const float*)d_in[2];
  const float* bias = (const float*)d_in[3];
  const float* hm = (const float*)d_in[4];
  const int* esrc = (const int*)d_in[5];
  const int* edst = (const int*)d_in[6];
  float* out = (float*)d_out;

  char* ws = (char*)d_ws;
  ushort_t* A2 = (ushort_t*)ws;    ws += 51200000;   // frag-layout A
  ushort_t* wct = (ushort_t*)ws;   ws += 524288;
  int* colb = (int*)ws;            ws += 8192;
  float* signb = (float*)ws;       ws += 8192;
  int* deg = (int*)ws;             ws += 200192;
  int* offsets = (int*)ws;         ws += 200704;
  int* cursor = (int*)ws;          ws += 200192;
  int* bsum = (int*)ws;            ws += 1024;
  int* boff = (int*)ws;            ws += 1024;
  int* csr = (int*)ws;             ws += 3200000;
  const size_t base_need = (size_t)(ws - (char*)d_ws);
  const int use_bf = (ws_size >= base_need + 25600000) ? 1 : 0;
  ushort_t* xbf = (ushort_t*)ws;   // 25.6 MB, only if use_bf

  hipMemsetAsync(deg, 0, (size_t)N_NODES * 4, stream);
  cvt_x_kernel<<<12500, 256, 0, stream>>>(x, A2, xbf, use_bf);
  deg_kernel<<<3125, 256, 0, stream>>>(edst, deg);
  scan_bsum_kernel<<<SCAN_BLOCKS, 256, 0, stream>>>(deg, bsum);
  scan_bscan_kernel<<<1, 256, 0, stream>>>(bsum, boff);
  scan_final_kernel<<<SCAN_BLOCKS, 256, 0, stream>>>(deg, boff, offsets, cursor);
  fill_kernel<<<3125, 256, 0, stream>>>(esrc, edst, cursor, csr);
  agg_kernel<<<12500, 256, 0, stream>>>(x, xbf, use_bf, offsets, csr, A2);
  extract_kernel<<<8, 256, 0, stream>>>(hm, colb, signb);
  build_wct_kernel<<<512, 256, 0, stream>>>(Wpost, Wself, colb, signb, wct);
  gemm_kernel<<<dim3(8 * SCAN_BLOCKS), 512, 0, stream>>>(A2, wct, bias, out);
}